// Round 8
// baseline (100.370 us; speedup 1.0000x reference)
//
#include <hip/hip_runtime.h>
#include <hip/hip_fp16.h>
#include <math.h>

#define EE 64
#define HH 128
#define DD 256
#define MHID 512
#define NSC 32
#define PPED 64
#define NTOT 2048
#define TILE 16
#define PPS 1024

typedef __attribute__((ext_vector_type(8))) short short8;
typedef __attribute__((ext_vector_type(4))) float f32x4;
typedef _Float16 half8 __attribute__((ext_vector_type(8)));

// workspace layout
//   floats [0, 2560): A0[512] A1[512] B0[512] B1[512] cvec[512]
//   floats [4096, +1048576): cat[2048][512] (cols 0..255 mx, 256..511 mn)
//   bytes  U16_OFF : U fp16 [2048][512]   (affine+hid+cvec folded)
//   bytes  W2T_OFF : Wm2^T bf16 [256][512]
//   bytes  WPT_OFF : Wp^T  bf16 [256][512]
//   bytes  PAIR_OFF: uint32 pairs[32][1024]
//   bytes  SCNT_OFF: uint32 scnt[32]
//   bytes  WM1BT_OFF: Wm1b^T fp16 [512][128]
static const int CATF = 4096;
static const size_t U16_OFF = (size_t)(CATF + NTOT * MHID) * 4;
static const size_t W2T_OFF = U16_OFF + (size_t)NTOT * MHID * 2;
static const size_t WPT_OFF = W2T_OFF + (size_t)DD * MHID * 2;
static const size_t PAIR_OFF = WPT_OFF + (size_t)DD * MHID * 2;
static const size_t SCNT_OFF = PAIR_OFF + (size_t)NSC * PPS * 4;
static const size_t WM1BT_OFF = SCNT_OFF + 256;

__device__ __forceinline__ unsigned short f2bf(float f) {
  unsigned int u = __float_as_uint(f);
  return (unsigned short)((u + 0x7fffu + ((u >> 16) & 1u)) >> 16);
}
__device__ __forceinline__ unsigned short f2h(float f) {
  return __half_as_ushort(__float2half(f));
}

// ====== k_prep: coeff fold + Wm2T/WpT (bf16) + Wm1bT (fp16). 66 blocks ======
__global__ __launch_bounds__(256) void k_prep(
    const float* __restrict__ Ws, const float* __restrict__ bs,
    const float* __restrict__ Wv, const float* __restrict__ bv,
    const float* __restrict__ Wm1, const float* __restrict__ bm1,
    const float* __restrict__ Wm2, const float* __restrict__ Wp,
    float* __restrict__ ws) {
  __shared__ unsigned short Tsh[16 * MHID];
  int b = blockIdx.x;
  int tid = threadIdx.x;
  if (b < 2) {
    int m = b * 256 + tid;
    float a0 = 0.f, a1 = 0.f, b0 = 0.f, b1 = 0.f, cs = 0.f, cv = 0.f;
    for (int e = 0; e < EE; ++e) {
      float w1 = Wm1[e * MHID + m];
      float w2 = Wm1[(EE + e) * MHID + m];
      a0 = fmaf(Ws[e], w1, a0);
      a1 = fmaf(Ws[EE + e], w1, a1);
      b0 = fmaf(Wv[e], w2, b0);
      b1 = fmaf(Wv[EE + e], w2, b1);
      cs = fmaf(bs[e], w1, cs);
      cv = fmaf(bv[e], w2, cv);
    }
    ws[m] = a0;
    ws[MHID + m] = a1;
    ws[2 * MHID + m] = b0;
    ws[3 * MHID + m] = b1;
    ws[4 * MHID + m] = bm1[m] + cs + cv;
  } else if (b < 34) {
    const float* src = (b < 18) ? Wm2 : Wp;
    unsigned short* dst = (unsigned short*)((char*)ws + ((b < 18) ? W2T_OFF : WPT_OFF));
    int c0 = ((b < 18) ? (b - 2) : (b - 18)) * 16;
#pragma unroll 4
    for (int it = 0; it < 32; ++it) {
      int k = it * 16 + (tid >> 4);
      int c = tid & 15;
      Tsh[c * MHID + k] = f2bf(src[(size_t)k * DD + c0 + c]);
    }
    __syncthreads();
    unsigned int* dst32 = (unsigned int*)dst;
#pragma unroll 4
    for (int it = 0; it < 16; ++it) {
      int flat = it * 256 + tid;
      int c = flat >> 8;
      int ku = flat & 255;
      unsigned int lo = Tsh[c * MHID + 2 * ku];
      unsigned int hi = Tsh[c * MHID + 2 * ku + 1];
      dst32[(size_t)(c0 + c) * (MHID / 2) + ku] = lo | (hi << 16);
    }
  } else {
    unsigned short* dst = (unsigned short*)((char*)ws + WM1BT_OFF);
    int c0 = (b - 34) * 16;
#pragma unroll
    for (int it = 0; it < 8; ++it) {
      int k = it * 16 + (tid >> 4);
      int c = tid & 15;
      Tsh[c * HH + k] = f2h(Wm1[(size_t)(2 * EE + k) * MHID + c0 + c]);
    }
    __syncthreads();
    unsigned int* dst32 = (unsigned int*)dst;
#pragma unroll
    for (int it = 0; it < 4; ++it) {
      int flat = it * 256 + tid;
      int c = flat >> 6;
      int ku = flat & 63;
      unsigned int lo = Tsh[c * HH + 2 * ku];
      unsigned int hi = Tsh[c * HH + 2 * ku + 1];
      dst32[(size_t)(c0 + c) * (HH / 2) + ku] = lo | (hi << 16);
    }
  }
}

// ====== k1m: U via MFMA f16 (blocks 0..255) + masks w/ scene compaction ======
__global__ __launch_bounds__(256) void k1m(
    const float* __restrict__ hstates, const float* __restrict__ pos,
    const float* __restrict__ vel, const float* __restrict__ bpos,
    float* __restrict__ ws) {
  __shared__ __align__(16) char raw[8448];
  int b = blockIdx.x;
  int tid = threadIdx.x;
  if (b < 256) {
    unsigned short* Ash = (unsigned short*)raw;
    const unsigned short* wm1bt = (const unsigned short*)((const char*)ws + WM1BT_OFF);
    unsigned short* u16 = (unsigned short*)((char*)ws + U16_OFF);
    int bx = b >> 2, by = b & 3;
    int n0 = bx * 32, C0 = by * 128;
    {
      int p = tid >> 3, kq = (tid & 7) * 16;
      const float* hp = hstates + (size_t)(n0 + p) * HH + kq;
      float4 f0 = *(const float4*)(hp);
      float4 f1 = *(const float4*)(hp + 4);
      float4 f2 = *(const float4*)(hp + 8);
      float4 f3 = *(const float4*)(hp + 12);
      int swz = (p & 7) << 3;
      uint4 v0, v1;
      v0.x = f2h(f0.x) | ((unsigned int)f2h(f0.y) << 16);
      v0.y = f2h(f0.z) | ((unsigned int)f2h(f0.w) << 16);
      v0.z = f2h(f1.x) | ((unsigned int)f2h(f1.y) << 16);
      v0.w = f2h(f1.z) | ((unsigned int)f2h(f1.w) << 16);
      v1.x = f2h(f2.x) | ((unsigned int)f2h(f2.y) << 16);
      v1.y = f2h(f2.z) | ((unsigned int)f2h(f2.w) << 16);
      v1.z = f2h(f3.x) | ((unsigned int)f2h(f3.y) << 16);
      v1.w = f2h(f3.z) | ((unsigned int)f2h(f3.w) << 16);
      *(uint4*)(Ash + ((p * HH + kq) ^ swz)) = v0;
      *(uint4*)(Ash + ((p * HH + kq + 8) ^ swz)) = v1;
    }
    __syncthreads();
    int w = tid >> 6, l = tid & 63;
    int lr = l & 15, lg = l >> 4;
    f32x4 acc[2][2];
#pragma unroll
    for (int i = 0; i < 2; ++i)
#pragma unroll
      for (int j = 0; j < 2; ++j) acc[i][j] = (f32x4){0.f, 0.f, 0.f, 0.f};
    int aswz = (lr & 7) << 3;
#pragma unroll
    for (int ks = 0; ks < 4; ++ks) {
      int k0 = ks * 32 + lg * 8;
      half8 a0 = *(const half8*)(Ash + ((lr * HH + k0) ^ aswz));
      half8 a1 = *(const half8*)(Ash + (((16 + lr) * HH + k0) ^ aswz));
      const unsigned short* bb = wm1bt + (size_t)(C0 + w * 32 + lr) * HH + k0;
      half8 b0 = *(const half8*)(bb);
      half8 b1 = *(const half8*)(bb + 16 * HH);
      acc[0][0] = __builtin_amdgcn_mfma_f32_16x16x32_f16(a0, b0, acc[0][0], 0, 0, 0);
      acc[0][1] = __builtin_amdgcn_mfma_f32_16x16x32_f16(a0, b1, acc[0][1], 0, 0, 0);
      acc[1][0] = __builtin_amdgcn_mfma_f32_16x16x32_f16(a1, b0, acc[1][0], 0, 0, 0);
      acc[1][1] = __builtin_amdgcn_mfma_f32_16x16x32_f16(a1, b1, acc[1][1], 0, 0, 0);
    }
#pragma unroll
    for (int ct = 0; ct < 2; ++ct) {
      int col = C0 + w * 32 + ct * 16 + lr;
      float a0c = ws[col], a1c = ws[MHID + col], b0c = ws[2 * MHID + col],
            b1c = ws[3 * MHID + col], cc = ws[4 * MHID + col];
#pragma unroll
      for (int rt = 0; rt < 2; ++rt) {
#pragma unroll
        for (int r = 0; r < 4; ++r) {
          int row = n0 + rt * 16 + lg * 4 + r;
          float px = pos[row * 2], py = pos[row * 2 + 1];
          float vx = vel[row * 2], vy = vel[row * 2 + 1];
          float uv = acc[rt][ct][r] + px * a0c + py * a1c + vx * b0c + vy * b1c + cc;
          u16[(size_t)row * MHID + col] = f2h(uv);
        }
      }
    }
  } else if (b < 288) {
    // visibility mask + per-scene compaction (no global atomics)
    double* sx = (double*)raw;
    double* sy = (double*)(raw + 512);
    int* cnt_sh = (int*)(raw + 1024);
    int* pref_sh = (int*)(raw + 1280);
    unsigned long long* mw_sh = (unsigned long long*)(raw + 1544);
    int scene = b - 256;
    int i = tid;
    int n = scene * PPED + i;
    double px = 0.0, py = 0.0, xb = 0.0, yb = 0.0;
    if (i < PPED) {
      px = (double)pos[n * 2];
      py = (double)pos[n * 2 + 1];
      sx[i] = px;
      sy[i] = py;
      xb = (double)bpos[n * 2];
      yb = (double)bpos[n * 2 + 1];
    }
    __syncthreads();
    unsigned long long mw = 0ull;
    if (i < PPED) {
      double xr = px - xb, yr = py - yb;
      double safe = (xr == 0.0) ? 1.0 : fabs(xr);
      double at = atan(fabs(yr) / safe);
      const double r90 = M_PI / 2.0, r180 = M_PI, r270 = 3.0 * M_PI / 2.0;
      double ang;
      if (xr > 0.0 && yr > 0.0) ang = at + r270;
      else if (xr < 0.0 && yr > 0.0) ang = r90 - at;
      else if (xr < 0.0 && yr < 0.0) ang = r90 + at;
      else if (xr > 0.0 && yr < 0.0) ang = r270 - at;
      else if (xr == 0.0 && yr > 0.0) ang = 0.0;
      else if (xr == 0.0 && yr < 0.0) ang = r180;
      else if (yr == 0.0 && xr > 0.0) ang = r270;
      else if (yr == 0.0 && xr < 0.0) ang = r90;
      else ang = 0.0;
      double cd = cos(ang), sd = sin(ang);
      const double cc2 = 2.0 / cos(60.0 * M_PI / 180.0);
      const double bb = sin(60.0 * M_PI / 180.0) * cc2;  // 2*sqrt(3)
      for (int j = 0; j < PPED; ++j) {
        if (j == i) continue;
        double dx = sx[j] - px, dy = sy[j] - py;
        double xt = cd * dx - sd * dy;
        double yt = sd * dx + cd * dy;
        double res = (yt >= 0.0) ? (xt * xt + yt * yt / 4.0) : (xt * xt + yt * yt);
        bool egg = (res <= 1.0);
        double c1 = 2.0 * xt + bb * yt;
        double c2 = 2.0 * xt - bb * yt;
        bool cone = (c1 > 0.0 && c2 < 0.0) || (c1 == 0.0) || (c2 == 0.0);
        if (egg && (yt >= 0.0) && cone) mw |= (1ull << j);
      }
      mw_sh[i] = mw;
      cnt_sh[i] = __popcll(mw);
    }
    __syncthreads();
    if (tid == 0) {
      int run = 0;
      for (int j = 0; j < PPED; ++j) {
        pref_sh[j] = run;
        run += cnt_sh[j];
      }
      ((unsigned int*)((char*)ws + SCNT_OFF))[scene] =
          (unsigned int)((run > PPS) ? PPS : run);
    }
    __syncthreads();
    if (i < PPED) {
      int c = cnt_sh[i];
      int basep = pref_sh[i];
      int lim = PPS - basep;
      if (lim < 0) lim = 0;
      if (lim > c) lim = c;
      unsigned int* pairs = (unsigned int*)((char*)ws + PAIR_OFF) + scene * PPS;
      unsigned long long rem = mw;
      unsigned int hi = ((unsigned int)n) << 16;
      for (int q = 0; q < lim; ++q) {
        int j = __builtin_ctzll(rem);
        rem &= rem - 1;
        pairs[basep + q] = hi | (unsigned int)(scene * PPED + j);
      }
    }
  }
}

// ====== kC: per-(scene, 64-col slice), sequential tiles, atomic-free pooling =====
__global__ __launch_bounds__(256) void kC(const float* __restrict__ ws,
                                          const float* __restrict__ pos,
                                          const float* __restrict__ vel,
                                          const float* __restrict__ bm2,
                                          float* __restrict__ cat) {
  int s = blockIdx.x >> 2, sl = blockIdx.x & 3;
  int c0 = sl * 64;
  int np = (int)((const unsigned int*)((const char*)ws + SCNT_OFF))[s];
  __shared__ __align__(16) float smem[5120];  // A bf16 16x512 swz (16KB) + H2[16][64]
  __shared__ int si[TILE], sjj[TILE];
  __shared__ float spv[TILE][4];
  __shared__ int seen[PPED];
  unsigned short* Ash = (unsigned short*)smem;
  float* H2 = smem + 4096;
  const unsigned short* u16 = (const unsigned short*)((const char*)ws + U16_OFF);
  const short* w2t = (const short*)((const char*)ws + W2T_OFF);
  const unsigned int* pairs = (const unsigned int*)((const char*)ws + PAIR_OFF) + s * PPS;
  int tid = threadIdx.x;
  if (tid < PPED) seen[tid] = 0;
  int w = tid >> 6, l = tid & 63;
  int lr = l & 15, lg = l >> 4;
  int mycol = c0 + w * 16 + lr;
  float bias = bm2[mycol];
  float rmx = 0.f, rmn = 0.f;
  int cur = -1;
  int nt = (np + TILE - 1) / TILE;
  for (int t = 0; t < nt; ++t) {
    int t0 = t * TILE;
    __syncthreads();  // prior scan done, seen init visible
    if (tid < TILE) {
      int p = t0 + tid;
      unsigned int pk = (p < np) ? pairs[p] : pairs[t0];
      int ii = (int)(pk >> 16), jj = (int)(pk & 0xFFFFu);
      si[tid] = ii;
      sjj[tid] = jj;
      spv[tid][0] = pos[ii * 2];
      spv[tid][1] = pos[ii * 2 + 1];
      spv[tid][2] = vel[ii * 2];
      spv[tid][3] = vel[ii * 2 + 1];
    }
    __syncthreads();
    // stage A: h1[pr][k] = relu(U[jj][k] - V_i[k]) -> bf16 swizzled
    {
      int pr = tid & 15, seg = tid >> 4;
      int jj = sjj[pr];
      float px = spv[pr][0], py = spv[pr][1], vx = spv[pr][2], vy = spv[pr][3];
      const unsigned short* Up = u16 + (size_t)jj * MHID + seg * 32;
      int swz = (pr & 7) << 3;
#pragma unroll
      for (int q = 0; q < 4; ++q) {
        int k0 = seg * 32 + q * 8;
        uint4 uv = *(const uint4*)(Up + q * 8);
        float4 c0a = *(const float4*)(ws + k0);
        float4 c0b = *(const float4*)(ws + k0 + 4);
        float4 c1a = *(const float4*)(ws + MHID + k0);
        float4 c1b = *(const float4*)(ws + MHID + k0 + 4);
        float4 c2a = *(const float4*)(ws + 2 * MHID + k0);
        float4 c2b = *(const float4*)(ws + 2 * MHID + k0 + 4);
        float4 c3a = *(const float4*)(ws + 3 * MHID + k0);
        float4 c3b = *(const float4*)(ws + 3 * MHID + k0 + 4);
        float u0 = __half2float(__ushort_as_half((unsigned short)(uv.x & 0xffff)));
        float u1 = __half2float(__ushort_as_half((unsigned short)(uv.x >> 16)));
        float u2 = __half2float(__ushort_as_half((unsigned short)(uv.y & 0xffff)));
        float u3 = __half2float(__ushort_as_half((unsigned short)(uv.y >> 16)));
        float u4 = __half2float(__ushort_as_half((unsigned short)(uv.z & 0xffff)));
        float u5 = __half2float(__ushort_as_half((unsigned short)(uv.z >> 16)));
        float u6 = __half2float(__ushort_as_half((unsigned short)(uv.w & 0xffff)));
        float u7 = __half2float(__ushort_as_half((unsigned short)(uv.w >> 16)));
        unsigned int h0 =
            f2bf(fmaxf(u0 - (px * c0a.x + py * c1a.x + vx * c2a.x + vy * c3a.x), 0.f));
        unsigned int h1 =
            f2bf(fmaxf(u1 - (px * c0a.y + py * c1a.y + vx * c2a.y + vy * c3a.y), 0.f));
        unsigned int h2 =
            f2bf(fmaxf(u2 - (px * c0a.z + py * c1a.z + vx * c2a.z + vy * c3a.z), 0.f));
        unsigned int h3 =
            f2bf(fmaxf(u3 - (px * c0a.w + py * c1a.w + vx * c2a.w + vy * c3a.w), 0.f));
        unsigned int h4 =
            f2bf(fmaxf(u4 - (px * c0b.x + py * c1b.x + vx * c2b.x + vy * c3b.x), 0.f));
        unsigned int h5 =
            f2bf(fmaxf(u5 - (px * c0b.y + py * c1b.y + vx * c2b.y + vy * c3b.y), 0.f));
        unsigned int h6 =
            f2bf(fmaxf(u6 - (px * c0b.z + py * c1b.z + vx * c2b.z + vy * c3b.z), 0.f));
        unsigned int h7 =
            f2bf(fmaxf(u7 - (px * c0b.w + py * c1b.w + vx * c2b.w + vy * c3b.w), 0.f));
        uint4 pk4;
        pk4.x = h0 | (h1 << 16);
        pk4.y = h2 | (h3 << 16);
        pk4.z = h4 | (h5 << 16);
        pk4.w = h6 | (h7 << 16);
        *(uint4*)(Ash + (((pr * MHID + k0)) ^ swz)) = pk4;
      }
    }
    __syncthreads();
    // MFMA: 16 pairs x 64 cols (this slice), K=512; 1 mfma/wave/ks
    f32x4 acc = {0.f, 0.f, 0.f, 0.f};
    int aswz = (lr & 7) << 3;
#pragma unroll 4
    for (int ks = 0; ks < 16; ++ks) {
      short8 a = *(const short8*)(Ash + ((lr * MHID + ks * 32 + lg * 8) ^ aswz));
      short8 bfr = *(const short8*)(w2t + (size_t)mycol * MHID + ks * 32 + lg * 8);
      acc = __builtin_amdgcn_mfma_f32_16x16x32_bf16(a, bfr, acc, 0, 0, 0);
    }
#pragma unroll
    for (int r = 0; r < 4; ++r)
      H2[(lg * 4 + r) * 64 + w * 16 + lr] = fmaxf(acc[r] + bias, 0.f);
    __syncthreads();
    // scan: threads 0..63, col = c0 + tid; run state persists across tiles
    if (tid < 64) {
      int lastv = np - t0;
      if (lastv > TILE) lastv = TILE;
      for (int r = 0; r < lastv; ++r) {
        int ii = si[r];
        float v = H2[r * 64 + tid];
        if (ii != cur) {
          if (cur >= 0) {
            float* mp = cat + (size_t)cur * 2 * DD + c0 + tid;
            mp[0] = rmx;
            mp[DD] = rmn;
          }
          if (tid == 0) seen[ii & 63] = 1;
          cur = ii;
          rmx = v;
          rmn = v;
        } else {
          rmx = fmaxf(rmx, v);
          rmn = fminf(rmn, v);
        }
      }
    }
  }
  if (tid < 64 && cur >= 0) {
    float* mp = cat + (size_t)cur * 2 * DD + c0 + tid;
    mp[0] = rmx;
    mp[DD] = rmn;
  }
  __syncthreads();
  // zero-fill unseen peds (this slice's columns)
  for (int i = w; i < PPED; i += 4) {
    if (!seen[i]) {
      float* mp = cat + (size_t)(s * PPED + i) * 2 * DD + c0 + l;
      mp[0] = 0.f;
      mp[DD] = 0.f;
    }
  }
}

// ====== kD: out = relu(cat @ Wp + bp) via MFMA (no sentinel needed) ======
__global__ __launch_bounds__(256) void kD(const float* __restrict__ ws,
                                          const float* __restrict__ bp,
                                          float* __restrict__ out) {
  const float* cat = ws + CATF;
  const short* wpt = (const short*)((const char*)ws + WPT_OFF);
  int m0 = blockIdx.x * 16;
  int tid = threadIdx.x;
  int w = tid >> 6, l = tid & 63;
  int arow = m0 + (l & 15), agrp = l >> 4;
  f32x4 acc0 = {0.f, 0.f, 0.f, 0.f}, acc1 = {0.f, 0.f, 0.f, 0.f};
  f32x4 acc2 = {0.f, 0.f, 0.f, 0.f}, acc3 = {0.f, 0.f, 0.f, 0.f};
#pragma unroll 4
  for (int ks = 0; ks < 16; ++ks) {
    const float* ap = cat + (size_t)arow * MHID + ks * 32 + agrp * 8;
    float4 fa = *(const float4*)(ap);
    float4 fb = *(const float4*)(ap + 4);
    union {
      unsigned int u[4];
      short8 s;
    } av;
    av.u[0] = (unsigned int)f2bf(fa.x) | ((unsigned int)f2bf(fa.y) << 16);
    av.u[1] = (unsigned int)f2bf(fa.z) | ((unsigned int)f2bf(fa.w) << 16);
    av.u[2] = (unsigned int)f2bf(fb.x) | ((unsigned int)f2bf(fb.y) << 16);
    av.u[3] = (unsigned int)f2bf(fb.z) | ((unsigned int)f2bf(fb.w) << 16);
    const short* bbase = wpt + (size_t)(w * 64 + (l & 15)) * MHID + ks * 32 + agrp * 8;
    short8 b0 = *(const short8*)(bbase);
    short8 b1 = *(const short8*)(bbase + 16 * MHID);
    short8 b2 = *(const short8*)(bbase + 32 * MHID);
    short8 b3 = *(const short8*)(bbase + 48 * MHID);
    acc0 = __builtin_amdgcn_mfma_f32_16x16x32_bf16(av.s, b0, acc0, 0, 0, 0);
    acc1 = __builtin_amdgcn_mfma_f32_16x16x32_bf16(av.s, b1, acc1, 0, 0, 0);
    acc2 = __builtin_amdgcn_mfma_f32_16x16x32_bf16(av.s, b2, acc2, 0, 0, 0);
    acc3 = __builtin_amdgcn_mfma_f32_16x16x32_bf16(av.s, b3, acc3, 0, 0, 0);
  }
#pragma unroll
  for (int t = 0; t < 4; ++t) {
    int col = (w * 4 + t) * 16 + (l & 15);
    float bias = bp[col];
    f32x4 av = (t == 0) ? acc0 : (t == 1) ? acc1 : (t == 2) ? acc2 : acc3;
#pragma unroll
    for (int r = 0; r < 4; ++r) {
      int row = m0 + (l >> 4) * 4 + r;
      out[(size_t)row * DD + col] = fmaxf(av[r] + bias, 0.f);
    }
  }
}

extern "C" void kernel_launch(void* const* d_in, const int* in_sizes, int n_in,
                              void* d_out, int out_size, void* d_ws, size_t ws_size,
                              hipStream_t stream) {
  const float* hstates = (const float*)d_in[0];
  const float* pos = (const float*)d_in[2];
  const float* vel = (const float*)d_in[3];
  const float* bpos = (const float*)d_in[4];
  const float* Ws = (const float*)d_in[5];
  const float* bs = (const float*)d_in[6];
  const float* Wv = (const float*)d_in[7];
  const float* bv = (const float*)d_in[8];
  const float* Wm1 = (const float*)d_in[9];
  const float* bm1 = (const float*)d_in[10];
  const float* Wm2 = (const float*)d_in[11];
  const float* bm2 = (const float*)d_in[12];
  const float* Wp = (const float*)d_in[13];
  const float* bp = (const float*)d_in[14];
  float* ws = (float*)d_ws;
  float* out = (float*)d_out;

  hipLaunchKernelGGL(k_prep, dim3(66), dim3(256), 0, stream, Ws, bs, Wv, bv, Wm1, bm1,
                     Wm2, Wp, ws);
  hipLaunchKernelGGL(k1m, dim3(288), dim3(256), 0, stream, hstates, pos, vel, bpos, ws);
  hipLaunchKernelGGL(kC, dim3(NSC * 4), dim3(256), 0, stream, ws, pos, vel, bm2,
                     ws + CATF);
  hipLaunchKernelGGL(kD, dim3(NTOT / 16), dim3(256), 0, stream, ws, bp, out);
}

// Round 9
// 67.880 us; speedup vs baseline: 1.4786x; 1.4786x over previous
//
#include <hip/hip_runtime.h>
#include <hip/hip_fp16.h>
#include <math.h>

#define EE 64
#define HH 128
#define DD 256
#define MHID 512
#define NSC 32
#define PPED 64
#define NTOT 2048
#define TILE 16
#define PPS 1024

typedef __attribute__((ext_vector_type(8))) short short8;
typedef __attribute__((ext_vector_type(4))) float f32x4;
typedef _Float16 half8 __attribute__((ext_vector_type(8)));

// workspace layout (bytes)
static const size_t U16_OFF = 16384;                              // fp16 U[2048][512]  (hid+own affine+cvec)
static const size_t V16_OFF = U16_OFF + (size_t)NTOT * MHID * 2;  // fp16 V[2048][512]  (own affine only)
static const size_t W2T_OFF = V16_OFF + (size_t)NTOT * MHID * 2;  // fp16 Wm2^T [256][512]
static const size_t WPT_OFF = W2T_OFF + (size_t)DD * MHID * 2;    // bf16 Wp^T  [256][512]
static const size_t WM1BT_OFF = WPT_OFF + (size_t)DD * MHID * 2;  // fp16 Wm1b^T [512][128]
static const size_t PAIR_OFF = WM1BT_OFF + (size_t)MHID * HH * 2; // u32 pairs[32][1024]
static const size_t SCNT_OFF = PAIR_OFF + (size_t)NSC * PPS * 4;  // u32 scnt[32]
static const size_t PSTART_OFF = SCNT_OFF + 4096;                 // u32 pstart[2048] (global H2 row)
static const size_t PCNT_OFF = PSTART_OFF + (size_t)NTOT * 4;     // u32 pcnt[2048]
static const size_t H2_OFF = PCNT_OFF + (size_t)NTOT * 4 + 4096;  // f32 H2[32*1024][256] = 32MB

__device__ __forceinline__ unsigned short f2bf(float f) {
  unsigned int u = __float_as_uint(f);
  return (unsigned short)((u + 0x7fffu + ((u >> 16) & 1u)) >> 16);
}
__device__ __forceinline__ unsigned short f2h(float f) {
  return __half_as_ushort(__float2half(f));
}

// ====== k_prep: coeff fold + W2T(fp16) + WpT(bf16) + Wm1bT(fp16). 66 blocks ======
__global__ __launch_bounds__(256) void k_prep(
    const float* __restrict__ Ws, const float* __restrict__ bs,
    const float* __restrict__ Wv, const float* __restrict__ bv,
    const float* __restrict__ Wm1, const float* __restrict__ bm1,
    const float* __restrict__ Wm2, const float* __restrict__ Wp,
    float* __restrict__ ws) {
  __shared__ unsigned short Tsh[16 * MHID];
  int b = blockIdx.x;
  int tid = threadIdx.x;
  if (b < 2) {
    int m = b * 256 + tid;
    float a0 = 0.f, a1 = 0.f, b0 = 0.f, b1 = 0.f, cs = 0.f, cv = 0.f;
    for (int e = 0; e < EE; ++e) {
      float w1 = Wm1[e * MHID + m];
      float w2 = Wm1[(EE + e) * MHID + m];
      a0 = fmaf(Ws[e], w1, a0);
      a1 = fmaf(Ws[EE + e], w1, a1);
      b0 = fmaf(Wv[e], w2, b0);
      b1 = fmaf(Wv[EE + e], w2, b1);
      cs = fmaf(bs[e], w1, cs);
      cv = fmaf(bv[e], w2, cv);
    }
    ws[m] = a0;
    ws[MHID + m] = a1;
    ws[2 * MHID + m] = b0;
    ws[3 * MHID + m] = b1;
    ws[4 * MHID + m] = bm1[m] + cs + cv;
  } else if (b < 34) {
    bool isW2 = (b < 18);
    const float* src = isW2 ? Wm2 : Wp;
    unsigned short* dst = (unsigned short*)((char*)ws + (isW2 ? W2T_OFF : WPT_OFF));
    int c0 = (isW2 ? (b - 2) : (b - 18)) * 16;
#pragma unroll 4
    for (int it = 0; it < 32; ++it) {
      int k = it * 16 + (tid >> 4);
      int c = tid & 15;
      float v = src[(size_t)k * DD + c0 + c];
      Tsh[c * MHID + k] = isW2 ? f2h(v) : f2bf(v);
    }
    __syncthreads();
    unsigned int* dst32 = (unsigned int*)dst;
#pragma unroll 4
    for (int it = 0; it < 16; ++it) {
      int flat = it * 256 + tid;
      int c = flat >> 8;
      int ku = flat & 255;
      unsigned int lo = Tsh[c * MHID + 2 * ku];
      unsigned int hi = Tsh[c * MHID + 2 * ku + 1];
      dst32[(size_t)(c0 + c) * (MHID / 2) + ku] = lo | (hi << 16);
    }
  } else {
    unsigned short* dst = (unsigned short*)((char*)ws + WM1BT_OFF);
    int c0 = (b - 34) * 16;
#pragma unroll
    for (int it = 0; it < 8; ++it) {
      int k = it * 16 + (tid >> 4);
      int c = tid & 15;
      Tsh[c * HH + k] = f2h(Wm1[(size_t)(2 * EE + k) * MHID + c0 + c]);
    }
    __syncthreads();
    unsigned int* dst32 = (unsigned int*)dst;
#pragma unroll
    for (int it = 0; it < 4; ++it) {
      int flat = it * 256 + tid;
      int c = flat >> 6;
      int ku = flat & 63;
      unsigned int lo = Tsh[c * HH + 2 * ku];
      unsigned int hi = Tsh[c * HH + 2 * ku + 1];
      dst32[(size_t)(c0 + c) * (HH / 2) + ku] = lo | (hi << 16);
    }
  }
}

// ====== k1m: U16/V16 via MFMA f16 (blocks 0..255) + masks (256..287) ======
__global__ __launch_bounds__(256) void k1m(
    const float* __restrict__ hstates, const float* __restrict__ pos,
    const float* __restrict__ vel, const float* __restrict__ bpos,
    float* __restrict__ ws) {
  __shared__ __align__(16) char raw[8448];
  int b = blockIdx.x;
  int tid = threadIdx.x;
  if (b < 256) {
    unsigned short* Ash = (unsigned short*)raw;
    const unsigned short* wm1bt = (const unsigned short*)((const char*)ws + WM1BT_OFF);
    unsigned short* u16 = (unsigned short*)((char*)ws + U16_OFF);
    unsigned short* v16 = (unsigned short*)((char*)ws + V16_OFF);
    int bx = b >> 2, by = b & 3;
    int n0 = bx * 32, C0 = by * 128;
    {
      int p = tid >> 3, kq = (tid & 7) * 16;
      const float* hp = hstates + (size_t)(n0 + p) * HH + kq;
      float4 f0 = *(const float4*)(hp);
      float4 f1 = *(const float4*)(hp + 4);
      float4 f2 = *(const float4*)(hp + 8);
      float4 f3 = *(const float4*)(hp + 12);
      int swz = (p & 7) << 3;
      uint4 v0, v1;
      v0.x = f2h(f0.x) | ((unsigned int)f2h(f0.y) << 16);
      v0.y = f2h(f0.z) | ((unsigned int)f2h(f0.w) << 16);
      v0.z = f2h(f1.x) | ((unsigned int)f2h(f1.y) << 16);
      v0.w = f2h(f1.z) | ((unsigned int)f2h(f1.w) << 16);
      v1.x = f2h(f2.x) | ((unsigned int)f2h(f2.y) << 16);
      v1.y = f2h(f2.z) | ((unsigned int)f2h(f2.w) << 16);
      v1.z = f2h(f3.x) | ((unsigned int)f2h(f3.y) << 16);
      v1.w = f2h(f3.z) | ((unsigned int)f2h(f3.w) << 16);
      *(uint4*)(Ash + ((p * HH + kq) ^ swz)) = v0;
      *(uint4*)(Ash + ((p * HH + kq + 8) ^ swz)) = v1;
    }
    __syncthreads();
    int w = tid >> 6, l = tid & 63;
    int lr = l & 15, lg = l >> 4;
    f32x4 acc[2][2];
#pragma unroll
    for (int i = 0; i < 2; ++i)
#pragma unroll
      for (int j = 0; j < 2; ++j) acc[i][j] = (f32x4){0.f, 0.f, 0.f, 0.f};
    int aswz = (lr & 7) << 3;
#pragma unroll
    for (int ks = 0; ks < 4; ++ks) {
      int k0 = ks * 32 + lg * 8;
      half8 a0 = *(const half8*)(Ash + ((lr * HH + k0) ^ aswz));
      half8 a1 = *(const half8*)(Ash + (((16 + lr) * HH + k0) ^ aswz));
      const unsigned short* bb = wm1bt + (size_t)(C0 + w * 32 + lr) * HH + k0;
      half8 b0 = *(const half8*)(bb);
      half8 b1 = *(const half8*)(bb + 16 * HH);
      acc[0][0] = __builtin_amdgcn_mfma_f32_16x16x32_f16(a0, b0, acc[0][0], 0, 0, 0);
      acc[0][1] = __builtin_amdgcn_mfma_f32_16x16x32_f16(a0, b1, acc[0][1], 0, 0, 0);
      acc[1][0] = __builtin_amdgcn_mfma_f32_16x16x32_f16(a1, b0, acc[1][0], 0, 0, 0);
      acc[1][1] = __builtin_amdgcn_mfma_f32_16x16x32_f16(a1, b1, acc[1][1], 0, 0, 0);
    }
#pragma unroll
    for (int ct = 0; ct < 2; ++ct) {
      int col = C0 + w * 32 + ct * 16 + lr;
      float a0c = ws[col], a1c = ws[MHID + col], b0c = ws[2 * MHID + col],
            b1c = ws[3 * MHID + col], cc = ws[4 * MHID + col];
#pragma unroll
      for (int rt = 0; rt < 2; ++rt) {
#pragma unroll
        for (int r = 0; r < 4; ++r) {
          int row = n0 + rt * 16 + lg * 4 + r;
          float px = pos[row * 2], py = pos[row * 2 + 1];
          float vx = vel[row * 2], vy = vel[row * 2 + 1];
          float base = px * a0c + py * a1c + vx * b0c + vy * b1c;
          u16[(size_t)row * MHID + col] = f2h(acc[rt][ct][r] + base + cc);
          v16[(size_t)row * MHID + col] = f2h(base);
        }
      }
    }
  } else if (b < 288) {
    double* sx = (double*)raw;
    double* sy = (double*)(raw + 512);
    int* cnt_sh = (int*)(raw + 1024);
    int* pref_sh = (int*)(raw + 1280);
    int scene = b - 256;
    int i = tid;
    int n = scene * PPED + i;
    double px = 0.0, py = 0.0, xb = 0.0, yb = 0.0;
    if (i < PPED) {
      px = (double)pos[n * 2];
      py = (double)pos[n * 2 + 1];
      sx[i] = px;
      sy[i] = py;
      xb = (double)bpos[n * 2];
      yb = (double)bpos[n * 2 + 1];
    }
    __syncthreads();
    unsigned long long mw = 0ull;
    if (i < PPED) {
      double xr = px - xb, yr = py - yb;
      double safe = (xr == 0.0) ? 1.0 : fabs(xr);
      double at = atan(fabs(yr) / safe);
      const double r90 = M_PI / 2.0, r180 = M_PI, r270 = 3.0 * M_PI / 2.0;
      double ang;
      if (xr > 0.0 && yr > 0.0) ang = at + r270;
      else if (xr < 0.0 && yr > 0.0) ang = r90 - at;
      else if (xr < 0.0 && yr < 0.0) ang = r90 + at;
      else if (xr > 0.0 && yr < 0.0) ang = r270 - at;
      else if (xr == 0.0 && yr > 0.0) ang = 0.0;
      else if (xr == 0.0 && yr < 0.0) ang = r180;
      else if (yr == 0.0 && xr > 0.0) ang = r270;
      else if (yr == 0.0 && xr < 0.0) ang = r90;
      else ang = 0.0;
      double cd = cos(ang), sd = sin(ang);
      const double cc2 = 2.0 / cos(60.0 * M_PI / 180.0);
      const double bb = sin(60.0 * M_PI / 180.0) * cc2;  // 2*sqrt(3)
      for (int j = 0; j < PPED; ++j) {
        if (j == i) continue;
        double dx = sx[j] - px, dy = sy[j] - py;
        double xt = cd * dx - sd * dy;
        double yt = sd * dx + cd * dy;
        double res = (yt >= 0.0) ? (xt * xt + yt * yt / 4.0) : (xt * xt + yt * yt);
        bool egg = (res <= 1.0);
        double c1 = 2.0 * xt + bb * yt;
        double c2 = 2.0 * xt - bb * yt;
        bool cone = (c1 > 0.0 && c2 < 0.0) || (c1 == 0.0) || (c2 == 0.0);
        if (egg && (yt >= 0.0) && cone) mw |= (1ull << j);
      }
      cnt_sh[i] = __popcll(mw);
    }
    __syncthreads();
    if (tid == 0) {
      int run = 0;
      for (int j = 0; j < PPED; ++j) {
        pref_sh[j] = run;
        run += cnt_sh[j];
      }
      ((unsigned int*)((char*)ws + SCNT_OFF))[scene] =
          (unsigned int)((run > PPS) ? PPS : run);
    }
    __syncthreads();
    if (i < PPED) {
      int c = cnt_sh[i];
      int basep = pref_sh[i];
      if (basep > PPS) basep = PPS;
      int lim = PPS - basep;
      if (lim > c) lim = c;
      ((unsigned int*)((char*)ws + PSTART_OFF))[n] = (unsigned int)(scene * PPS + basep);
      ((unsigned int*)((char*)ws + PCNT_OFF))[n] = (unsigned int)lim;
      unsigned int* pairs = (unsigned int*)((char*)ws + PAIR_OFF) + scene * PPS;
      unsigned long long rem = mw;
      unsigned int hi = ((unsigned int)n) << 16;
      for (int q = 0; q < lim; ++q) {
        int j = __builtin_ctzll(rem);
        rem &= rem - 1;
        pairs[basep + q] = hi | (unsigned int)(scene * PPED + j);
      }
    }
  }
}

// ====== kC: per (scene, colgroup, tile-slot): layer2 GEMM -> H2 fp32 ======
__global__ __launch_bounds__(256) void kC(const float* __restrict__ ws,
                                          const float* __restrict__ bm2) {
  int bid = blockIdx.x;
  int s = bid >> 5;
  int cg = bid & 3;
  int bt0 = (bid >> 2) & 7;
  int np = (int)((const unsigned int*)((const char*)ws + SCNT_OFF))[s];
  if (bt0 * TILE >= np) return;
  __shared__ __align__(16) unsigned short Ash[16 * MHID];  // 16 KB fp16, XOR-swizzled
  __shared__ int si[TILE], sjj[TILE];
  const unsigned short* u16 = (const unsigned short*)((const char*)ws + U16_OFF);
  const unsigned short* v16 = (const unsigned short*)((const char*)ws + V16_OFF);
  const _Float16* w2t = (const _Float16*)((const char*)ws + W2T_OFF);
  float* H2 = (float*)((char*)ws + H2_OFF);
  const unsigned int* pairs =
      (const unsigned int*)((const char*)ws + PAIR_OFF) + s * PPS;
  int tid = threadIdx.x;
  int w = tid >> 6, l = tid & 63;
  int lr = l & 15, lg = l >> 4;
  int mycol = cg * 64 + w * 16 + lr;
  // preload all 16 B-frags (their latency hides under A staging)
  half8 bfr[16];
#pragma unroll
  for (int ks = 0; ks < 16; ++ks)
    bfr[ks] = *(const half8*)(w2t + (size_t)mycol * MHID + ks * 32 + lg * 8);
  float bias = bm2[mycol];
  for (int t = bt0; t * TILE < np; t += 8) {
    int t0 = t * TILE;
    if (t != bt0) __syncthreads();  // protect Ash from previous iteration readers
    if (tid < TILE) {
      int p = t0 + tid;
      unsigned int pk = (p < np) ? pairs[p] : pairs[t0];
      si[tid] = (int)(pk >> 16);
      sjj[tid] = (int)(pk & 0xFFFFu);
    }
    __syncthreads();
    // stage A: h1 = relu(U16[j] - V16[i]) fp16, 8 loads/thread
    {
      int pr = tid & 15, seg = tid >> 4;
      int jj = sjj[pr], ii = si[pr];
      const unsigned short* Up = u16 + (size_t)jj * MHID + seg * 32;
      const unsigned short* Vp = v16 + (size_t)ii * MHID + seg * 32;
      int swz = (pr & 7) << 3;
#pragma unroll
      for (int q = 0; q < 4; ++q) {
        half8 hu = *(const half8*)(Up + q * 8);
        half8 hv = *(const half8*)(Vp + q * 8);
        half8 d;
#pragma unroll
        for (int e = 0; e < 8; ++e) {
          _Float16 x = hu[e] - hv[e];
          d[e] = (x > (_Float16)0) ? x : (_Float16)0;
        }
        *(half8*)(Ash + ((pr * MHID + seg * 32 + q * 8) ^ swz)) = d;
      }
    }
    __syncthreads();
    f32x4 acc = {0.f, 0.f, 0.f, 0.f};
    int aswz = (lr & 7) << 3;
#pragma unroll
    for (int ks = 0; ks < 16; ++ks) {
      half8 a = *(const half8*)(Ash + ((lr * MHID + ks * 32 + lg * 8) ^ aswz));
      acc = __builtin_amdgcn_mfma_f32_16x16x32_f16(a, bfr[ks], acc, 0, 0, 0);
    }
    float* hrow = H2 + (size_t)(s * PPS + t0 + lg * 4) * DD + mycol;
#pragma unroll
    for (int r = 0; r < 4; ++r) hrow[(size_t)r * DD] = fmaxf(acc[r] + bias, 0.f);
  }
}

// ====== kD: pool (H2 -> cat tile in LDS) + final GEMM via MFMA ======
__global__ __launch_bounds__(256) void kD(const float* __restrict__ ws,
                                          const float* __restrict__ bp,
                                          float* __restrict__ out) {
  __shared__ __align__(16) float catt[16 * 512 + 32];  // XOR-swizzled cat tile
  int m0 = blockIdx.x * 16;
  int tid = threadIdx.x;
  const float* H2 = (const float*)((const char*)ws + H2_OFF);
  const unsigned int* pstart = (const unsigned int*)((const char*)ws + PSTART_OFF);
  const unsigned int* pcnt = (const unsigned int*)((const char*)ws + PCNT_OFF);
  const short* wpt = (const short*)((const char*)ws + WPT_OFF);
  // phase 1: pooling, thread owns column tid of each of 16 rows
#pragma unroll 4
  for (int rr = 0; rr < 16; ++rr) {
    int n = m0 + rr;
    int ps = (int)pstart[n], pc = (int)pcnt[n];
    float mx = 0.f, mn = 0.f;
    if (pc > 0) {
      const float* hp = H2 + (size_t)ps * DD + tid;
      mx = hp[0];
      mn = mx;
      for (int r = 1; r < pc; ++r) {
        float v = hp[(size_t)r * DD];
        mx = fmaxf(mx, v);
        mn = fminf(mn, v);
      }
    }
    int swz = (rr & 7) << 2;
    catt[(rr * 512 + tid) ^ swz] = mx;
    catt[(rr * 512 + 256 + tid) ^ swz] = mn;
  }
  __syncthreads();
  // phase 2: GEMM from catt (bf16 A on the fly) x WpT
  int w = tid >> 6, l = tid & 63;
  int arow = l & 15, agrp = l >> 4;
  int aswz = (arow & 7) << 2;
  f32x4 acc0 = {0.f, 0.f, 0.f, 0.f}, acc1 = {0.f, 0.f, 0.f, 0.f};
  f32x4 acc2 = {0.f, 0.f, 0.f, 0.f}, acc3 = {0.f, 0.f, 0.f, 0.f};
#pragma unroll 4
  for (int ks = 0; ks < 16; ++ks) {
    int base = arow * 512 + ks * 32 + agrp * 8;
    float4 fa = *(const float4*)(catt + (base ^ aswz));
    float4 fb = *(const float4*)(catt + ((base + 4) ^ aswz));
    union {
      unsigned int u[4];
      short8 s;
    } av;
    av.u[0] = (unsigned int)f2bf(fa.x) | ((unsigned int)f2bf(fa.y) << 16);
    av.u[1] = (unsigned int)f2bf(fa.z) | ((unsigned int)f2bf(fa.w) << 16);
    av.u[2] = (unsigned int)f2bf(fb.x) | ((unsigned int)f2bf(fb.y) << 16);
    av.u[3] = (unsigned int)f2bf(fb.z) | ((unsigned int)f2bf(fb.w) << 16);
    const short* bbase = wpt + (size_t)(w * 64 + arow) * MHID + ks * 32 + agrp * 8;
    short8 b0 = *(const short8*)(bbase);
    short8 b1 = *(const short8*)(bbase + 16 * MHID);
    short8 b2 = *(const short8*)(bbase + 32 * MHID);
    short8 b3 = *(const short8*)(bbase + 48 * MHID);
    acc0 = __builtin_amdgcn_mfma_f32_16x16x32_bf16(av.s, b0, acc0, 0, 0, 0);
    acc1 = __builtin_amdgcn_mfma_f32_16x16x32_bf16(av.s, b1, acc1, 0, 0, 0);
    acc2 = __builtin_amdgcn_mfma_f32_16x16x32_bf16(av.s, b2, acc2, 0, 0, 0);
    acc3 = __builtin_amdgcn_mfma_f32_16x16x32_bf16(av.s, b3, acc3, 0, 0, 0);
  }
#pragma unroll
  for (int t = 0; t < 4; ++t) {
    int col = (w * 4 + t) * 16 + arow;
    float bias = bp[col];
    f32x4 av = (t == 0) ? acc0 : (t == 1) ? acc1 : (t == 2) ? acc2 : acc3;
#pragma unroll
    for (int r = 0; r < 4; ++r) {
      int row = m0 + (l >> 4) * 4 + r;
      out[(size_t)row * DD + col] = fmaxf(av[r] + bias, 0.f);
    }
  }
}

extern "C" void kernel_launch(void* const* d_in, const int* in_sizes, int n_in,
                              void* d_out, int out_size, void* d_ws, size_t ws_size,
                              hipStream_t stream) {
  const float* hstates = (const float*)d_in[0];
  const float* pos = (const float*)d_in[2];
  const float* vel = (const float*)d_in[3];
  const float* bpos = (const float*)d_in[4];
  const float* Ws = (const float*)d_in[5];
  const float* bs = (const float*)d_in[6];
  const float* Wv = (const float*)d_in[7];
  const float* bv = (const float*)d_in[8];
  const float* Wm1 = (const float*)d_in[9];
  const float* bm1 = (const float*)d_in[10];
  const float* Wm2 = (const float*)d_in[11];
  const float* bm2 = (const float*)d_in[12];
  const float* Wp = (const float*)d_in[13];
  const float* bp = (const float*)d_in[14];
  float* ws = (float*)d_ws;
  float* out = (float*)d_out;

  hipLaunchKernelGGL(k_prep, dim3(66), dim3(256), 0, stream, Ws, bs, Wv, bv, Wm1, bm1,
                     Wm2, Wp, ws);
  hipLaunchKernelGGL(k1m, dim3(288), dim3(256), 0, stream, hstates, pos, vel, bpos, ws);
  hipLaunchKernelGGL(kC, dim3(NSC * 32), dim3(256), 0, stream, ws, bm2);
  hipLaunchKernelGGL(kD, dim3(NTOT / 16), dim3(256), 0, stream, ws, bp, out);
}

// Round 10
// 63.051 us; speedup vs baseline: 1.5919x; 1.0766x over previous
//
#include <hip/hip_runtime.h>
#include <hip/hip_fp16.h>
#include <math.h>

#define EE 64
#define HH 128
#define DD 256
#define MHID 512
#define NSC 32
#define PPED 64
#define NTOT 2048
#define TILE 16
#define PPS 1024

typedef __attribute__((ext_vector_type(8))) short short8;
typedef __attribute__((ext_vector_type(4))) float f32x4;
typedef _Float16 half8 __attribute__((ext_vector_type(8)));

// workspace layout (bytes)
// Weight layouts are FRAG-BLOCKED: element (col, k) with k = ks*32 + g*8 + e
// stored at col*512 + g*128 + ks*8 + e  (so a thread's 16 ks-frags for fixed
// (col,g) are 256B contiguous).  Wm1bT: k = ks*32+g*8+e (ks<4) stored at
// col*128 + g*32 + ks*8 + e.
static const size_t U16_OFF = 16384;                              // fp16 U[2048][512]
static const size_t V16_OFF = U16_OFF + (size_t)NTOT * MHID * 2;  // fp16 V[2048][512]
static const size_t W2T_OFF = V16_OFF + (size_t)NTOT * MHID * 2;  // fp16 Wm2^T frag-blocked
static const size_t WPT_OFF = W2T_OFF + (size_t)DD * MHID * 2;    // bf16 Wp^T frag-blocked
static const size_t WM1BT_OFF = WPT_OFF + (size_t)DD * MHID * 2;  // fp16 Wm1b^T frag-blocked
static const size_t PAIR_OFF = WM1BT_OFF + (size_t)MHID * HH * 2; // u32 pairs[32][1024]
static const size_t SCNT_OFF = PAIR_OFF + (size_t)NSC * PPS * 4;  // u32 scnt[32]
static const size_t PSTART_OFF = SCNT_OFF + 4096;                 // u32 pstart[2048]
static const size_t PCNT_OFF = PSTART_OFF + (size_t)NTOT * 4;     // u32 pcnt[2048]
static const size_t H2_OFF = PCNT_OFF + (size_t)NTOT * 4 + 4096;  // f32 H2[32*1024][256]

__device__ __forceinline__ unsigned short f2bf(float f) {
  unsigned int u = __float_as_uint(f);
  return (unsigned short)((u + 0x7fffu + ((u >> 16) & 1u)) >> 16);
}
__device__ __forceinline__ unsigned short f2h(float f) {
  return __half_as_ushort(__float2half(f));
}

// ====== k_prep: coeff fold + W2T(fp16)/WpT(bf16)/Wm1bT(fp16) frag-blocked ======
__global__ __launch_bounds__(256) void k_prep(
    const float* __restrict__ Ws, const float* __restrict__ bs,
    const float* __restrict__ Wv, const float* __restrict__ bv,
    const float* __restrict__ Wm1, const float* __restrict__ bm1,
    const float* __restrict__ Wm2, const float* __restrict__ Wp,
    float* __restrict__ ws) {
  __shared__ unsigned short Tsh[16 * MHID];
  int b = blockIdx.x;
  int tid = threadIdx.x;
  if (b < 2) {
    int m = b * 256 + tid;
    float a0 = 0.f, a1 = 0.f, b0 = 0.f, b1 = 0.f, cs = 0.f, cv = 0.f;
    for (int e = 0; e < EE; ++e) {
      float w1 = Wm1[e * MHID + m];
      float w2 = Wm1[(EE + e) * MHID + m];
      a0 = fmaf(Ws[e], w1, a0);
      a1 = fmaf(Ws[EE + e], w1, a1);
      b0 = fmaf(Wv[e], w2, b0);
      b1 = fmaf(Wv[EE + e], w2, b1);
      cs = fmaf(bs[e], w1, cs);
      cv = fmaf(bv[e], w2, cv);
    }
    ws[m] = a0;
    ws[MHID + m] = a1;
    ws[2 * MHID + m] = b0;
    ws[3 * MHID + m] = b1;
    ws[4 * MHID + m] = bm1[m] + cs + cv;
  } else if (b < 34) {
    bool isW2 = (b < 18);
    const float* src = isW2 ? Wm2 : Wp;
    unsigned short* dst = (unsigned short*)((char*)ws + (isW2 ? W2T_OFF : WPT_OFF));
    int c0 = (isW2 ? (b - 2) : (b - 18)) * 16;
#pragma unroll 4
    for (int it = 0; it < 32; ++it) {
      int k = it * 16 + (tid >> 4);
      int c = tid & 15;
      float v = src[(size_t)k * DD + c0 + c];
      Tsh[c * MHID + k] = isW2 ? f2h(v) : f2bf(v);
    }
    __syncthreads();
    unsigned int* dst32 = (unsigned int*)dst;
#pragma unroll 4
    for (int it = 0; it < 16; ++it) {
      int flat = it * 256 + tid;
      int c = flat >> 8;
      int ku = flat & 255;  // k = 2*ku
      unsigned int lo = Tsh[c * MHID + 2 * ku];
      unsigned int hi = Tsh[c * MHID + 2 * ku + 1];
      int ks = ku >> 4;          // k>>5
      int g = (ku >> 2) & 3;     // (k>>3)&3
      int r = ku & 3;            // (k&7)/2
      dst32[(size_t)(c0 + c) * 256 + g * 64 + ks * 4 + r] = lo | (hi << 16);
    }
  } else {
    unsigned short* dst = (unsigned short*)((char*)ws + WM1BT_OFF);
    int c0 = (b - 34) * 16;
#pragma unroll
    for (int it = 0; it < 8; ++it) {
      int k = it * 16 + (tid >> 4);
      int c = tid & 15;
      Tsh[c * HH + k] = f2h(Wm1[(size_t)(2 * EE + k) * MHID + c0 + c]);
    }
    __syncthreads();
    unsigned int* dst32 = (unsigned int*)dst;
#pragma unroll
    for (int it = 0; it < 4; ++it) {
      int flat = it * 256 + tid;
      int c = flat >> 6;
      int ku = flat & 63;  // k = 2*ku, k < 128
      unsigned int lo = Tsh[c * HH + 2 * ku];
      unsigned int hi = Tsh[c * HH + 2 * ku + 1];
      int ks = ku >> 4;         // k>>5 (0..3)
      int g = (ku >> 2) & 3;    // (k>>3)&3
      int r = ku & 3;
      dst32[(size_t)(c0 + c) * 64 + g * 16 + ks * 4 + r] = lo | (hi << 16);
    }
  }
}

// ====== k1m: U16/V16 via MFMA f16 (blocks 0..255) + masks (256..287) ======
__global__ __launch_bounds__(256) void k1m(
    const float* __restrict__ hstates, const float* __restrict__ pos,
    const float* __restrict__ vel, const float* __restrict__ bpos,
    float* __restrict__ ws) {
  __shared__ __align__(16) char raw[8448];
  int b = blockIdx.x;
  int tid = threadIdx.x;
  if (b < 256) {
    unsigned short* Ash = (unsigned short*)raw;
    const unsigned short* wm1bt = (const unsigned short*)((const char*)ws + WM1BT_OFF);
    unsigned short* u16 = (unsigned short*)((char*)ws + U16_OFF);
    unsigned short* v16 = (unsigned short*)((char*)ws + V16_OFF);
    int bx = b >> 2, by = b & 3;
    int n0 = bx * 32, C0 = by * 128;
    {
      int p = tid >> 3, kq = (tid & 7) * 16;
      const float* hp = hstates + (size_t)(n0 + p) * HH + kq;
      float4 f0 = *(const float4*)(hp);
      float4 f1 = *(const float4*)(hp + 4);
      float4 f2 = *(const float4*)(hp + 8);
      float4 f3 = *(const float4*)(hp + 12);
      int swz = (p & 7) << 3;
      uint4 v0, v1;
      v0.x = f2h(f0.x) | ((unsigned int)f2h(f0.y) << 16);
      v0.y = f2h(f0.z) | ((unsigned int)f2h(f0.w) << 16);
      v0.z = f2h(f1.x) | ((unsigned int)f2h(f1.y) << 16);
      v0.w = f2h(f1.z) | ((unsigned int)f2h(f1.w) << 16);
      v1.x = f2h(f2.x) | ((unsigned int)f2h(f2.y) << 16);
      v1.y = f2h(f2.z) | ((unsigned int)f2h(f2.w) << 16);
      v1.z = f2h(f3.x) | ((unsigned int)f2h(f3.y) << 16);
      v1.w = f2h(f3.z) | ((unsigned int)f2h(f3.w) << 16);
      *(uint4*)(Ash + ((p * HH + kq) ^ swz)) = v0;
      *(uint4*)(Ash + ((p * HH + kq + 8) ^ swz)) = v1;
    }
    __syncthreads();
    int w = tid >> 6, l = tid & 63;
    int lr = l & 15, lg = l >> 4;
    f32x4 acc[2][2];
#pragma unroll
    for (int i = 0; i < 2; ++i)
#pragma unroll
      for (int j = 0; j < 2; ++j) acc[i][j] = (f32x4){0.f, 0.f, 0.f, 0.f};
    int aswz = (lr & 7) << 3;
    // frag-blocked Wm1bT: frag(col, ks, g=lg) at col*128 + lg*32 + ks*8
    const unsigned short* bb0 = wm1bt + (size_t)(C0 + w * 32 + lr) * HH + lg * 32;
    const unsigned short* bb1 = bb0 + 16 * HH;
#pragma unroll
    for (int ks = 0; ks < 4; ++ks) {
      int k0 = ks * 32 + lg * 8;
      half8 a0 = *(const half8*)(Ash + ((lr * HH + k0) ^ aswz));
      half8 a1 = *(const half8*)(Ash + (((16 + lr) * HH + k0) ^ aswz));
      half8 b0 = *(const half8*)(bb0 + ks * 8);
      half8 b1 = *(const half8*)(bb1 + ks * 8);
      acc[0][0] = __builtin_amdgcn_mfma_f32_16x16x32_f16(a0, b0, acc[0][0], 0, 0, 0);
      acc[0][1] = __builtin_amdgcn_mfma_f32_16x16x32_f16(a0, b1, acc[0][1], 0, 0, 0);
      acc[1][0] = __builtin_amdgcn_mfma_f32_16x16x32_f16(a1, b0, acc[1][0], 0, 0, 0);
      acc[1][1] = __builtin_amdgcn_mfma_f32_16x16x32_f16(a1, b1, acc[1][1], 0, 0, 0);
    }
#pragma unroll
    for (int ct = 0; ct < 2; ++ct) {
      int col = C0 + w * 32 + ct * 16 + lr;
      float a0c = ws[col], a1c = ws[MHID + col], b0c = ws[2 * MHID + col],
            b1c = ws[3 * MHID + col], cc = ws[4 * MHID + col];
#pragma unroll
      for (int rt = 0; rt < 2; ++rt) {
#pragma unroll
        for (int r = 0; r < 4; ++r) {
          int row = n0 + rt * 16 + lg * 4 + r;
          float px = pos[row * 2], py = pos[row * 2 + 1];
          float vx = vel[row * 2], vy = vel[row * 2 + 1];
          float base = px * a0c + py * a1c + vx * b0c + vy * b1c;
          u16[(size_t)row * MHID + col] = f2h(acc[rt][ct][r] + base + cc);
          v16[(size_t)row * MHID + col] = f2h(base);
        }
      }
    }
  } else if (b < 288) {
    // mask: 256 threads = (i = tid&63, jg = tid>>6); 4x parallel over j
    double* sx = (double*)raw;
    double* sy = (double*)(raw + 512);
    int* cnt_sh = (int*)(raw + 1024);
    int* pref_sh = (int*)(raw + 1280);
    unsigned long long* mwp = (unsigned long long*)(raw + 1536);  // [4][64]
    int scene = b - 256;
    int i = tid & 63;
    int jg = tid >> 6;
    int n = scene * PPED + i;
    if (tid < PPED) {
      sx[i] = (double)pos[n * 2];
      sy[i] = (double)pos[n * 2 + 1];
    }
    __syncthreads();
    {
      double px = sx[i], py = sy[i];
      double xb = (double)bpos[n * 2], yb = (double)bpos[n * 2 + 1];
      double xr = px - xb, yr = py - yb;
      double safe = (xr == 0.0) ? 1.0 : fabs(xr);
      double at = atan(fabs(yr) / safe);
      const double r90 = M_PI / 2.0, r180 = M_PI, r270 = 3.0 * M_PI / 2.0;
      double ang;
      if (xr > 0.0 && yr > 0.0) ang = at + r270;
      else if (xr < 0.0 && yr > 0.0) ang = r90 - at;
      else if (xr < 0.0 && yr < 0.0) ang = r90 + at;
      else if (xr > 0.0 && yr < 0.0) ang = r270 - at;
      else if (xr == 0.0 && yr > 0.0) ang = 0.0;
      else if (xr == 0.0 && yr < 0.0) ang = r180;
      else if (yr == 0.0 && xr > 0.0) ang = r270;
      else if (yr == 0.0 && xr < 0.0) ang = r90;
      else ang = 0.0;
      double cd = cos(ang), sd = sin(ang);
      const double cc2 = 2.0 / cos(60.0 * M_PI / 180.0);
      const double bb = sin(60.0 * M_PI / 180.0) * cc2;  // 2*sqrt(3)
      unsigned long long mw = 0ull;
      for (int j = jg * 16; j < jg * 16 + 16; ++j) {
        if (j == i) continue;
        double dx = sx[j] - px, dy = sy[j] - py;
        double xt = cd * dx - sd * dy;
        double yt = sd * dx + cd * dy;
        double res = (yt >= 0.0) ? (xt * xt + yt * yt / 4.0) : (xt * xt + yt * yt);
        bool egg = (res <= 1.0);
        double c1 = 2.0 * xt + bb * yt;
        double c2 = 2.0 * xt - bb * yt;
        bool cone = (c1 > 0.0 && c2 < 0.0) || (c1 == 0.0) || (c2 == 0.0);
        if (egg && (yt >= 0.0) && cone) mw |= (1ull << j);
      }
      mwp[jg * 64 + i] = mw;
    }
    __syncthreads();
    unsigned long long mw = 0ull;
    if (tid < PPED) {
      mw = mwp[i] | mwp[64 + i] | mwp[128 + i] | mwp[192 + i];
      cnt_sh[i] = __popcll(mw);
    }
    __syncthreads();
    if (tid == 0) {
      int run = 0;
      for (int j = 0; j < PPED; ++j) {
        pref_sh[j] = run;
        run += cnt_sh[j];
      }
      ((unsigned int*)((char*)ws + SCNT_OFF))[scene] =
          (unsigned int)((run > PPS) ? PPS : run);
    }
    __syncthreads();
    if (tid < PPED) {
      int c = cnt_sh[i];
      int basep = pref_sh[i];
      if (basep > PPS) basep = PPS;
      int lim = PPS - basep;
      if (lim > c) lim = c;
      ((unsigned int*)((char*)ws + PSTART_OFF))[n] = (unsigned int)(scene * PPS + basep);
      ((unsigned int*)((char*)ws + PCNT_OFF))[n] = (unsigned int)lim;
      unsigned int* pairs = (unsigned int*)((char*)ws + PAIR_OFF) + scene * PPS;
      unsigned long long rem = mw;
      unsigned int hi = ((unsigned int)n) << 16;
      for (int q = 0; q < lim; ++q) {
        int j = __builtin_ctzll(rem);
        rem &= rem - 1;
        pairs[basep + q] = hi | (unsigned int)(scene * PPED + j);
      }
    }
  }
}

// ====== kC: per (scene, colgroup, tile-slot): layer2 GEMM -> H2 fp32 ======
__global__ __launch_bounds__(256) void kC(const float* __restrict__ ws,
                                          const float* __restrict__ bm2) {
  int bid = blockIdx.x;
  int s = bid >> 5;
  int cg = bid & 3;
  int bt0 = (bid >> 2) & 7;
  int np = (int)((const unsigned int*)((const char*)ws + SCNT_OFF))[s];
  if (bt0 * TILE >= np) return;
  __shared__ __align__(16) unsigned short Ash[16 * MHID];
  __shared__ int si[TILE], sjj[TILE];
  const unsigned short* u16 = (const unsigned short*)((const char*)ws + U16_OFF);
  const unsigned short* v16 = (const unsigned short*)((const char*)ws + V16_OFF);
  const _Float16* w2t = (const _Float16*)((const char*)ws + W2T_OFF);
  float* H2 = (float*)((char*)ws + H2_OFF);
  const unsigned int* pairs =
      (const unsigned int*)((const char*)ws + PAIR_OFF) + s * PPS;
  int tid = threadIdx.x;
  int w = tid >> 6, l = tid & 63;
  int lr = l & 15, lg = l >> 4;
  int mycol = cg * 64 + w * 16 + lr;
  // frag-blocked W2T: thread's 16 frags contiguous (256B)
  const _Float16* w2b = w2t + (size_t)mycol * MHID + lg * 128;
  half8 bfr[16];
#pragma unroll
  for (int ks = 0; ks < 16; ++ks) bfr[ks] = *(const half8*)(w2b + ks * 8);
  float bias = bm2[mycol];
  for (int t = bt0; t * TILE < np; t += 8) {
    int t0 = t * TILE;
    if (t != bt0) __syncthreads();
    if (tid < TILE) {
      int p = t0 + tid;
      unsigned int pk = (p < np) ? pairs[p] : pairs[t0];
      si[tid] = (int)(pk >> 16);
      sjj[tid] = (int)(pk & 0xFFFFu);
    }
    __syncthreads();
    {
      int pr = tid & 15, seg = tid >> 4;
      int jj = sjj[pr], ii = si[pr];
      const unsigned short* Up = u16 + (size_t)jj * MHID + seg * 32;
      const unsigned short* Vp = v16 + (size_t)ii * MHID + seg * 32;
      int swz = (pr & 7) << 3;
#pragma unroll
      for (int q = 0; q < 4; ++q) {
        half8 hu = *(const half8*)(Up + q * 8);
        half8 hv = *(const half8*)(Vp + q * 8);
        half8 d;
#pragma unroll
        for (int e = 0; e < 8; ++e) {
          _Float16 x = hu[e] - hv[e];
          d[e] = (x > (_Float16)0) ? x : (_Float16)0;
        }
        *(half8*)(Ash + ((pr * MHID + seg * 32 + q * 8) ^ swz)) = d;
      }
    }
    __syncthreads();
    f32x4 acc = {0.f, 0.f, 0.f, 0.f};
    int aswz = (lr & 7) << 3;
#pragma unroll
    for (int ks = 0; ks < 16; ++ks) {
      half8 a = *(const half8*)(Ash + ((lr * MHID + ks * 32 + lg * 8) ^ aswz));
      acc = __builtin_amdgcn_mfma_f32_16x16x32_f16(a, bfr[ks], acc, 0, 0, 0);
    }
    float* hrow = H2 + (size_t)(s * PPS + t0 + lg * 4) * DD + mycol;
#pragma unroll
    for (int r = 0; r < 4; ++r) hrow[(size_t)r * DD] = fmaxf(acc[r] + bias, 0.f);
  }
}

// ====== kD: pool (H2 -> cat tile in LDS) + final GEMM via MFMA ======
__global__ __launch_bounds__(256) void kD(const float* __restrict__ ws,
                                          const float* __restrict__ bp,
                                          float* __restrict__ out) {
  __shared__ __align__(16) float catt[16 * 512 + 32];
  int m0 = blockIdx.x * 16;
  int tid = threadIdx.x;
  const float* H2 = (const float*)((const char*)ws + H2_OFF);
  const unsigned int* pstart = (const unsigned int*)((const char*)ws + PSTART_OFF);
  const unsigned int* pcnt = (const unsigned int*)((const char*)ws + PCNT_OFF);
  const short* wpt = (const short*)((const char*)ws + WPT_OFF);
#pragma unroll 4
  for (int rr = 0; rr < 16; ++rr) {
    int n = m0 + rr;
    int ps = (int)pstart[n], pc = (int)pcnt[n];
    float mx = 0.f, mn = 0.f;
    if (pc > 0) {
      const float* hp = H2 + (size_t)ps * DD + tid;
      mx = hp[0];
      mn = mx;
      for (int r = 1; r < pc; ++r) {
        float v = hp[(size_t)r * DD];
        mx = fmaxf(mx, v);
        mn = fminf(mn, v);
      }
    }
    int swz = (rr & 7) << 2;
    catt[(rr * 512 + tid) ^ swz] = mx;
    catt[(rr * 512 + 256 + tid) ^ swz] = mn;
  }
  __syncthreads();
  int w = tid >> 6, l = tid & 63;
  int arow = l & 15, agrp = l >> 4;
  int aswz = (arow & 7) << 2;
  // frag-blocked WpT bases for the 4 col-frags
  const short* wpb0 = wpt + (size_t)(w * 64 + arow) * MHID + agrp * 128;
  f32x4 acc0 = {0.f, 0.f, 0.f, 0.f}, acc1 = {0.f, 0.f, 0.f, 0.f};
  f32x4 acc2 = {0.f, 0.f, 0.f, 0.f}, acc3 = {0.f, 0.f, 0.f, 0.f};
#pragma unroll 4
  for (int ks = 0; ks < 16; ++ks) {
    int base = arow * 512 + ks * 32 + agrp * 8;
    float4 fa = *(const float4*)(catt + (base ^ aswz));
    float4 fb = *(const float4*)(catt + ((base + 4) ^ aswz));
    union {
      unsigned int u[4];
      short8 s;
    } av;
    av.u[0] = (unsigned int)f2bf(fa.x) | ((unsigned int)f2bf(fa.y) << 16);
    av.u[1] = (unsigned int)f2bf(fa.z) | ((unsigned int)f2bf(fa.w) << 16);
    av.u[2] = (unsigned int)f2bf(fb.x) | ((unsigned int)f2bf(fb.y) << 16);
    av.u[3] = (unsigned int)f2bf(fb.z) | ((unsigned int)f2bf(fb.w) << 16);
    short8 b0 = *(const short8*)(wpb0 + ks * 8);
    short8 b1 = *(const short8*)(wpb0 + 16 * MHID + ks * 8);
    short8 b2 = *(const short8*)(wpb0 + 32 * MHID + ks * 8);
    short8 b3 = *(const short8*)(wpb0 + 48 * MHID + ks * 8);
    acc0 = __builtin_amdgcn_mfma_f32_16x16x32_bf16(av.s, b0, acc0, 0, 0, 0);
    acc1 = __builtin_amdgcn_mfma_f32_16x16x32_bf16(av.s, b1, acc1, 0, 0, 0);
    acc2 = __builtin_amdgcn_mfma_f32_16x16x32_bf16(av.s, b2, acc2, 0, 0, 0);
    acc3 = __builtin_amdgcn_mfma_f32_16x16x32_bf16(av.s, b3, acc3, 0, 0, 0);
  }
#pragma unroll
  for (int t = 0; t < 4; ++t) {
    int col = (w * 4 + t) * 16 + arow;
    float bias = bp[col];
    f32x4 av = (t == 0) ? acc0 : (t == 1) ? acc1 : (t == 2) ? acc2 : acc3;
#pragma unroll
    for (int r = 0; r < 4; ++r) {
      int row = m0 + (l >> 4) * 4 + r;
      out[(size_t)row * DD + col] = fmaxf(av[r] + bias, 0.f);
    }
  }
}

extern "C" void kernel_launch(void* const* d_in, const int* in_sizes, int n_in,
                              void* d_out, int out_size, void* d_ws, size_t ws_size,
                              hipStream_t stream) {
  const float* hstates = (const float*)d_in[0];
  const float* pos = (const float*)d_in[2];
  const float* vel = (const float*)d_in[3];
  const float* bpos = (const float*)d_in[4];
  const float* Ws = (const float*)d_in[5];
  const float* bs = (const float*)d_in[6];
  const float* Wv = (const float*)d_in[7];
  const float* bv = (const float*)d_in[8];
  const float* Wm1 = (const float*)d_in[9];
  const float* bm1 = (const float*)d_in[10];
  const float* Wm2 = (const float*)d_in[11];
  const float* bm2 = (const float*)d_in[12];
  const float* Wp = (const float*)d_in[13];
  const float* bp = (const float*)d_in[14];
  float* ws = (float*)d_ws;
  float* out = (float*)d_out;

  hipLaunchKernelGGL(k_prep, dim3(66), dim3(256), 0, stream, Ws, bs, Wv, bv, Wm1, bm1,
                     Wm2, Wp, ws);
  hipLaunchKernelGGL(k1m, dim3(288), dim3(256), 0, stream, hstates, pos, vel, bpos, ws);
  hipLaunchKernelGGL(kC, dim3(NSC * 32), dim3(256), 0, stream, ws, bm2);
  hipLaunchKernelGGL(kD, dim3(NTOT / 16), dim3(256), 0, stream, ws, bp, out);
}

// Round 11
// 58.908 us; speedup vs baseline: 1.7038x; 1.0703x over previous
//
#include <hip/hip_runtime.h>
#include <hip/hip_fp16.h>
#include <math.h>

#define EE 64
#define HH 128
#define DD 256
#define MHID 512
#define NSC 32
#define PPED 64
#define NTOT 2048
#define TILE 16
#define PPS 1024

typedef __attribute__((ext_vector_type(8))) short short8;
typedef __attribute__((ext_vector_type(4))) float f32x4;
typedef _Float16 half8 __attribute__((ext_vector_type(8)));

// workspace layout (bytes)
// W2T/WPT are FRAG-BLOCKED: element (col,k), k = ks*32+g*8+e  ->  col*512 + g*128 + ks*8 + e
static const size_t U16_OFF = 16384;                              // fp16 U[2048][512]
static const size_t V16_OFF = U16_OFF + (size_t)NTOT * MHID * 2;  // fp16 V[2048][512]
static const size_t W2T_OFF = V16_OFF + (size_t)NTOT * MHID * 2;  // fp16 Wm2^T frag-blocked
static const size_t WPT_OFF = W2T_OFF + (size_t)DD * MHID * 2;    // bf16 Wp^T frag-blocked
static const size_t PAIR_OFF = WPT_OFF + (size_t)DD * MHID * 2;   // u32 pairs[32][1024]
static const size_t SCNT_OFF = PAIR_OFF + (size_t)NSC * PPS * 4;  // u32 scnt[32]
static const size_t PSTART_OFF = SCNT_OFF + 4096;                 // u32 pstart[2048]
static const size_t PCNT_OFF = PSTART_OFF + (size_t)NTOT * 4;     // u32 pcnt[2048]
static const size_t H2_OFF = PCNT_OFF + (size_t)NTOT * 4 + 4096;  // f32 H2[32*1024][256]

__device__ __forceinline__ unsigned short f2bf(float f) {
  unsigned int u = __float_as_uint(f);
  return (unsigned short)((u + 0x7fffu + ((u >> 16) & 1u)) >> 16);
}
__device__ __forceinline__ unsigned short f2h(float f) {
  return __half_as_ushort(__float2half(f));
}

// ====== kA: self-contained U/V GEMM (0..255) + masks (256..287) +
//            W2T (288..303) + WpT (304..319) ======
__global__ __launch_bounds__(256) void kA(
    const float* __restrict__ hstates, const float* __restrict__ pos,
    const float* __restrict__ vel, const float* __restrict__ bpos,
    const float* __restrict__ Ws, const float* __restrict__ bs,
    const float* __restrict__ Wv, const float* __restrict__ bv,
    const float* __restrict__ Wm1, const float* __restrict__ bm1,
    const float* __restrict__ Wm2, const float* __restrict__ Wp,
    float* __restrict__ ws) {
  __shared__ __align__(16) char smem[44544];
  int b = blockIdx.x;
  int tid = threadIdx.x;
  if (b < 256) {
    // ---------------- U/V via MFMA f16, fully self-contained ----------------
    unsigned short* Ash = (unsigned short*)smem;                 // hid fp16 swz, 8448B
    _Float16* Bsh = (_Float16*)(smem + 8448);                    // [128][130] (33280B)
    float* csh = (float*)(smem + 8448 + 33280);                  // [5][128]
    unsigned short* u16 = (unsigned short*)((char*)ws + U16_OFF);
    unsigned short* v16 = (unsigned short*)((char*)ws + V16_OFF);
    int bx = b >> 2, by = b & 3;
    int n0 = bx * 32, C0 = by * 128;
    // stage hid -> Ash (fp16, XOR-swizzled)
    {
      int p = tid >> 3, kq = (tid & 7) * 16;
      const float* hp = hstates + (size_t)(n0 + p) * HH + kq;
      float4 f0 = *(const float4*)(hp);
      float4 f1 = *(const float4*)(hp + 4);
      float4 f2 = *(const float4*)(hp + 8);
      float4 f3 = *(const float4*)(hp + 12);
      int swz = (p & 7) << 3;
      uint4 v0, v1;
      v0.x = f2h(f0.x) | ((unsigned int)f2h(f0.y) << 16);
      v0.y = f2h(f0.z) | ((unsigned int)f2h(f0.w) << 16);
      v0.z = f2h(f1.x) | ((unsigned int)f2h(f1.y) << 16);
      v0.w = f2h(f1.z) | ((unsigned int)f2h(f1.w) << 16);
      v1.x = f2h(f2.x) | ((unsigned int)f2h(f2.y) << 16);
      v1.y = f2h(f2.z) | ((unsigned int)f2h(f2.w) << 16);
      v1.z = f2h(f3.x) | ((unsigned int)f2h(f3.y) << 16);
      v1.w = f2h(f3.z) | ((unsigned int)f2h(f3.w) << 16);
      *(uint4*)(Ash + ((p * HH + kq) ^ swz)) = v0;
      *(uint4*)(Ash + ((p * HH + kq + 8) ^ swz)) = v1;
    }
    // stage Wm1b slab [128k][128col] -> Bsh fp16 (row stride 130)
#pragma unroll 4
    for (int it = 0; it < 16; ++it) {
      int flat = it * 1024 + tid * 4;
      int k = flat >> 7, col = flat & 127;
      float4 f = *(const float4*)&Wm1[(size_t)(2 * EE + k) * MHID + C0 + col];
      unsigned int* d = (unsigned int*)&Bsh[k * 130 + col];
      d[0] = (unsigned int)f2h(f.x) | ((unsigned int)f2h(f.y) << 16);
      d[1] = (unsigned int)f2h(f.z) | ((unsigned int)f2h(f.w) << 16);
    }
    // redundant coeff fold for this block's 128 cols (fp32, coalesced)
    if (tid < 128) {
      int col = C0 + tid;
      float a0 = 0.f, a1 = 0.f, b0 = 0.f, b1 = 0.f, cs = 0.f, cv = 0.f;
      for (int e = 0; e < EE; ++e) {
        float w1 = Wm1[(size_t)e * MHID + col];
        float w2 = Wm1[(size_t)(EE + e) * MHID + col];
        a0 = fmaf(Ws[e], w1, a0);
        a1 = fmaf(Ws[EE + e], w1, a1);
        b0 = fmaf(Wv[e], w2, b0);
        b1 = fmaf(Wv[EE + e], w2, b1);
        cs = fmaf(bs[e], w1, cs);
        cv = fmaf(bv[e], w2, cv);
      }
      csh[tid] = a0;
      csh[128 + tid] = a1;
      csh[256 + tid] = b0;
      csh[384 + tid] = b1;
      csh[512 + tid] = bm1[col] + cs + cv;
    }
    __syncthreads();
    int w = tid >> 6, l = tid & 63;
    int lr = l & 15, lg = l >> 4;
    f32x4 acc[2][2];
#pragma unroll
    for (int i = 0; i < 2; ++i)
#pragma unroll
      for (int j = 0; j < 2; ++j) acc[i][j] = (f32x4){0.f, 0.f, 0.f, 0.f};
    int aswz = (lr & 7) << 3;
    int colr0 = w * 32 + lr, colr1 = colr0 + 16;
#pragma unroll
    for (int ks = 0; ks < 4; ++ks) {
      int k0 = ks * 32 + lg * 8;
      half8 a0 = *(const half8*)(Ash + ((lr * HH + k0) ^ aswz));
      half8 a1 = *(const half8*)(Ash + (((16 + lr) * HH + k0) ^ aswz));
      half8 b0, b1;
#pragma unroll
      for (int e = 0; e < 8; ++e) {
        b0[e] = Bsh[(k0 + e) * 130 + colr0];
        b1[e] = Bsh[(k0 + e) * 130 + colr1];
      }
      acc[0][0] = __builtin_amdgcn_mfma_f32_16x16x32_f16(a0, b0, acc[0][0], 0, 0, 0);
      acc[0][1] = __builtin_amdgcn_mfma_f32_16x16x32_f16(a0, b1, acc[0][1], 0, 0, 0);
      acc[1][0] = __builtin_amdgcn_mfma_f32_16x16x32_f16(a1, b0, acc[1][0], 0, 0, 0);
      acc[1][1] = __builtin_amdgcn_mfma_f32_16x16x32_f16(a1, b1, acc[1][1], 0, 0, 0);
    }
#pragma unroll
    for (int ct = 0; ct < 2; ++ct) {
      int colr = w * 32 + ct * 16 + lr;
      int col = C0 + colr;
      float a0c = csh[colr], a1c = csh[128 + colr], b0c = csh[256 + colr],
            b1c = csh[384 + colr], cc = csh[512 + colr];
#pragma unroll
      for (int rt = 0; rt < 2; ++rt) {
#pragma unroll
        for (int r = 0; r < 4; ++r) {
          int row = n0 + rt * 16 + lg * 4 + r;
          float px = pos[row * 2], py = pos[row * 2 + 1];
          float vx = vel[row * 2], vy = vel[row * 2 + 1];
          float base = px * a0c + py * a1c + vx * b0c + vy * b1c;
          u16[(size_t)row * MHID + col] = f2h(acc[rt][ct][r] + base + cc);
          v16[(size_t)row * MHID + col] = f2h(base);
        }
      }
    }
  } else if (b < 288) {
    // ---------------- masks: (i = tid&63, jg = tid>>6), 4x parallel ----------------
    char* raw = smem;
    double* sx = (double*)raw;
    double* sy = (double*)(raw + 512);
    int* cnt_sh = (int*)(raw + 1024);
    int* pref_sh = (int*)(raw + 1280);
    unsigned long long* mwp = (unsigned long long*)(raw + 1536);  // [4][64]
    int scene = b - 256;
    int i = tid & 63;
    int jg = tid >> 6;
    int n = scene * PPED + i;
    if (tid < PPED) {
      sx[i] = (double)pos[n * 2];
      sy[i] = (double)pos[n * 2 + 1];
    }
    __syncthreads();
    {
      double px = sx[i], py = sy[i];
      double xb = (double)bpos[n * 2], yb = (double)bpos[n * 2 + 1];
      double xr = px - xb, yr = py - yb;
      double safe = (xr == 0.0) ? 1.0 : fabs(xr);
      double at = atan(fabs(yr) / safe);
      const double r90 = M_PI / 2.0, r180 = M_PI, r270 = 3.0 * M_PI / 2.0;
      double ang;
      if (xr > 0.0 && yr > 0.0) ang = at + r270;
      else if (xr < 0.0 && yr > 0.0) ang = r90 - at;
      else if (xr < 0.0 && yr < 0.0) ang = r90 + at;
      else if (xr > 0.0 && yr < 0.0) ang = r270 - at;
      else if (xr == 0.0 && yr > 0.0) ang = 0.0;
      else if (xr == 0.0 && yr < 0.0) ang = r180;
      else if (yr == 0.0 && xr > 0.0) ang = r270;
      else if (yr == 0.0 && xr < 0.0) ang = r90;
      else ang = 0.0;
      double cd = cos(ang), sd = sin(ang);
      const double cc2 = 2.0 / cos(60.0 * M_PI / 180.0);
      const double bb = sin(60.0 * M_PI / 180.0) * cc2;  // 2*sqrt(3)
      unsigned long long mw = 0ull;
      for (int j = jg * 16; j < jg * 16 + 16; ++j) {
        if (j == i) continue;
        double dx = sx[j] - px, dy = sy[j] - py;
        double xt = cd * dx - sd * dy;
        double yt = sd * dx + cd * dy;
        double res = (yt >= 0.0) ? (xt * xt + yt * yt / 4.0) : (xt * xt + yt * yt);
        bool egg = (res <= 1.0);
        double c1 = 2.0 * xt + bb * yt;
        double c2 = 2.0 * xt - bb * yt;
        bool cone = (c1 > 0.0 && c2 < 0.0) || (c1 == 0.0) || (c2 == 0.0);
        if (egg && (yt >= 0.0) && cone) mw |= (1ull << j);
      }
      mwp[jg * 64 + i] = mw;
    }
    __syncthreads();
    unsigned long long mw = 0ull;
    if (tid < PPED) {
      mw = mwp[i] | mwp[64 + i] | mwp[128 + i] | mwp[192 + i];
      cnt_sh[i] = __popcll(mw);
    }
    __syncthreads();
    if (tid == 0) {
      int run = 0;
      for (int j = 0; j < PPED; ++j) {
        pref_sh[j] = run;
        run += cnt_sh[j];
      }
      ((unsigned int*)((char*)ws + SCNT_OFF))[scene] =
          (unsigned int)((run > PPS) ? PPS : run);
    }
    __syncthreads();
    if (tid < PPED) {
      int c = cnt_sh[i];
      int basep = pref_sh[i];
      if (basep > PPS) basep = PPS;
      int lim = PPS - basep;
      if (lim > c) lim = c;
      ((unsigned int*)((char*)ws + PSTART_OFF))[n] = (unsigned int)(scene * PPS + basep);
      ((unsigned int*)((char*)ws + PCNT_OFF))[n] = (unsigned int)lim;
      unsigned int* pairs = (unsigned int*)((char*)ws + PAIR_OFF) + scene * PPS;
      unsigned long long rem = mw;
      unsigned int hi = ((unsigned int)n) << 16;
      for (int q = 0; q < lim; ++q) {
        int j = __builtin_ctzll(rem);
        rem &= rem - 1;
        pairs[basep + q] = hi | (unsigned int)(scene * PPED + j);
      }
    }
  } else {
    // ---------------- W2T(fp16) / WpT(bf16), frag-blocked ----------------
    unsigned short* Tsh = (unsigned short*)smem;
    bool isW2 = (b < 304);
    const float* src = isW2 ? Wm2 : Wp;
    unsigned short* dst = (unsigned short*)((char*)ws + (isW2 ? W2T_OFF : WPT_OFF));
    int c0 = (isW2 ? (b - 288) : (b - 304)) * 16;
#pragma unroll 4
    for (int it = 0; it < 32; ++it) {
      int k = it * 16 + (tid >> 4);
      int c = tid & 15;
      float v = src[(size_t)k * DD + c0 + c];
      Tsh[c * MHID + k] = isW2 ? f2h(v) : f2bf(v);
    }
    __syncthreads();
    unsigned int* dst32 = (unsigned int*)dst;
#pragma unroll 4
    for (int it = 0; it < 16; ++it) {
      int flat = it * 256 + tid;
      int c = flat >> 8;
      int ku = flat & 255;  // k = 2*ku
      unsigned int lo = Tsh[c * MHID + 2 * ku];
      unsigned int hi = Tsh[c * MHID + 2 * ku + 1];
      int ks = ku >> 4;
      int g = (ku >> 2) & 3;
      int r = ku & 3;
      dst32[(size_t)(c0 + c) * 256 + g * 64 + ks * 4 + r] = lo | (hi << 16);
    }
  }
}

// ====== kC: per (scene, colgroup, tile-slot): layer2 GEMM -> H2 fp32 ======
__global__ __launch_bounds__(256) void kC(const float* __restrict__ ws,
                                          const float* __restrict__ bm2) {
  int bid = blockIdx.x;
  int s = bid >> 5;
  int cg = bid & 3;
  int bt0 = (bid >> 2) & 7;
  int np = (int)((const unsigned int*)((const char*)ws + SCNT_OFF))[s];
  if (bt0 * TILE >= np) return;
  __shared__ __align__(16) unsigned short Ash[16 * MHID];
  __shared__ int si[TILE], sjj[TILE];
  const unsigned short* u16 = (const unsigned short*)((const char*)ws + U16_OFF);
  const unsigned short* v16 = (const unsigned short*)((const char*)ws + V16_OFF);
  const _Float16* w2t = (const _Float16*)((const char*)ws + W2T_OFF);
  float* H2 = (float*)((char*)ws + H2_OFF);
  const unsigned int* pairs =
      (const unsigned int*)((const char*)ws + PAIR_OFF) + s * PPS;
  int tid = threadIdx.x;
  int w = tid >> 6, l = tid & 63;
  int lr = l & 15, lg = l >> 4;
  int mycol = cg * 64 + w * 16 + lr;
  const _Float16* w2b = w2t + (size_t)mycol * MHID + lg * 128;
  half8 bfr[16];
#pragma unroll
  for (int ks = 0; ks < 16; ++ks) bfr[ks] = *(const half8*)(w2b + ks * 8);
  float bias = bm2[mycol];
  for (int t = bt0; t * TILE < np; t += 8) {
    int t0 = t * TILE;
    if (t != bt0) __syncthreads();
    if (tid < TILE) {
      int p = t0 + tid;
      unsigned int pk = (p < np) ? pairs[p] : pairs[t0];
      si[tid] = (int)(pk >> 16);
      sjj[tid] = (int)(pk & 0xFFFFu);
    }
    __syncthreads();
    {
      int pr = tid & 15, seg = tid >> 4;
      int jj = sjj[pr], ii = si[pr];
      const unsigned short* Up = u16 + (size_t)jj * MHID + seg * 32;
      const unsigned short* Vp = v16 + (size_t)ii * MHID + seg * 32;
      int swz = (pr & 7) << 3;
#pragma unroll
      for (int q = 0; q < 4; ++q) {
        half8 hu = *(const half8*)(Up + q * 8);
        half8 hv = *(const half8*)(Vp + q * 8);
        half8 d;
#pragma unroll
        for (int e = 0; e < 8; ++e) {
          _Float16 x = hu[e] - hv[e];
          d[e] = (x > (_Float16)0) ? x : (_Float16)0;
        }
        *(half8*)(Ash + ((pr * MHID + seg * 32 + q * 8) ^ swz)) = d;
      }
    }
    __syncthreads();
    f32x4 acc = {0.f, 0.f, 0.f, 0.f};
    int aswz = (lr & 7) << 3;
#pragma unroll
    for (int ks = 0; ks < 16; ++ks) {
      half8 a = *(const half8*)(Ash + ((lr * MHID + ks * 32 + lg * 8) ^ aswz));
      acc = __builtin_amdgcn_mfma_f32_16x16x32_f16(a, bfr[ks], acc, 0, 0, 0);
    }
    float* hrow = H2 + (size_t)(s * PPS + t0 + lg * 4) * DD + mycol;
#pragma unroll
    for (int r = 0; r < 4; ++r) hrow[(size_t)r * DD] = fmaxf(acc[r] + bias, 0.f);
  }
}

// ====== kD: pool (H2 -> cat tile in LDS) + final GEMM via MFMA ======
__global__ __launch_bounds__(256) void kD(const float* __restrict__ ws,
                                          const float* __restrict__ bp,
                                          float* __restrict__ out) {
  __shared__ __align__(16) float catt[16 * 512 + 32];
  int m0 = blockIdx.x * 16;
  int tid = threadIdx.x;
  const float* H2 = (const float*)((const char*)ws + H2_OFF);
  const unsigned int* pstart = (const unsigned int*)((const char*)ws + PSTART_OFF);
  const unsigned int* pcnt = (const unsigned int*)((const char*)ws + PCNT_OFF);
  const short* wpt = (const short*)((const char*)ws + WPT_OFF);
#pragma unroll 4
  for (int rr = 0; rr < 16; ++rr) {
    int n = m0 + rr;
    int ps = (int)pstart[n], pc = (int)pcnt[n];
    float mx = 0.f, mn = 0.f;
    if (pc > 0) {
      const float* hp = H2 + (size_t)ps * DD + tid;
      mx = hp[0];
      mn = mx;
      for (int r = 1; r < pc; ++r) {
        float v = hp[(size_t)r * DD];
        mx = fmaxf(mx, v);
        mn = fminf(mn, v);
      }
    }
    int swz = (rr & 7) << 2;
    catt[(rr * 512 + tid) ^ swz] = mx;
    catt[(rr * 512 + 256 + tid) ^ swz] = mn;
  }
  __syncthreads();
  int w = tid >> 6, l = tid & 63;
  int arow = l & 15, agrp = l >> 4;
  int aswz = (arow & 7) << 2;
  const short* wpb0 = wpt + (size_t)(w * 64 + arow) * MHID + agrp * 128;
  f32x4 acc0 = {0.f, 0.f, 0.f, 0.f}, acc1 = {0.f, 0.f, 0.f, 0.f};
  f32x4 acc2 = {0.f, 0.f, 0.f, 0.f}, acc3 = {0.f, 0.f, 0.f, 0.f};
#pragma unroll 4
  for (int ks = 0; ks < 16; ++ks) {
    int base = arow * 512 + ks * 32 + agrp * 8;
    float4 fa = *(const float4*)(catt + (base ^ aswz));
    float4 fb = *(const float4*)(catt + ((base + 4) ^ aswz));
    union {
      unsigned int u[4];
      short8 s;
    } av;
    av.u[0] = (unsigned int)f2bf(fa.x) | ((unsigned int)f2bf(fa.y) << 16);
    av.u[1] = (unsigned int)f2bf(fa.z) | ((unsigned int)f2bf(fa.w) << 16);
    av.u[2] = (unsigned int)f2bf(fb.x) | ((unsigned int)f2bf(fb.y) << 16);
    av.u[3] = (unsigned int)f2bf(fb.z) | ((unsigned int)f2bf(fb.w) << 16);
    short8 b0 = *(const short8*)(wpb0 + ks * 8);
    short8 b1 = *(const short8*)(wpb0 + 16 * MHID + ks * 8);
    short8 b2 = *(const short8*)(wpb0 + 32 * MHID + ks * 8);
    short8 b3 = *(const short8*)(wpb0 + 48 * MHID + ks * 8);
    acc0 = __builtin_amdgcn_mfma_f32_16x16x32_bf16(av.s, b0, acc0, 0, 0, 0);
    acc1 = __builtin_amdgcn_mfma_f32_16x16x32_bf16(av.s, b1, acc1, 0, 0, 0);
    acc2 = __builtin_amdgcn_mfma_f32_16x16x32_bf16(av.s, b2, acc2, 0, 0, 0);
    acc3 = __builtin_amdgcn_mfma_f32_16x16x32_bf16(av.s, b3, acc3, 0, 0, 0);
  }
#pragma unroll
  for (int t = 0; t < 4; ++t) {
    int col = (w * 4 + t) * 16 + arow;
    float bias = bp[col];
    f32x4 av = (t == 0) ? acc0 : (t == 1) ? acc1 : (t == 2) ? acc2 : acc3;
#pragma unroll
    for (int r = 0; r < 4; ++r) {
      int row = m0 + (l >> 4) * 4 + r;
      out[(size_t)row * DD + col] = fmaxf(av[r] + bias, 0.f);
    }
  }
}

extern "C" void kernel_launch(void* const* d_in, const int* in_sizes, int n_in,
                              void* d_out, int out_size, void* d_ws, size_t ws_size,
                              hipStream_t stream) {
  const float* hstates = (const float*)d_in[0];
  const float* pos = (const float*)d_in[2];
  const float* vel = (const float*)d_in[3];
  const float* bpos = (const float*)d_in[4];
  const float* Ws = (const float*)d_in[5];
  const float* bs = (const float*)d_in[6];
  const float* Wv = (const float*)d_in[7];
  const float* bv = (const float*)d_in[8];
  const float* Wm1 = (const float*)d_in[9];
  const float* bm1 = (const float*)d_in[10];
  const float* Wm2 = (const float*)d_in[11];
  const float* bm2 = (const float*)d_in[12];
  const float* Wp = (const float*)d_in[13];
  const float* bp = (const float*)d_in[14];
  float* ws = (float*)d_ws;
  float* out = (float*)d_out;

  hipLaunchKernelGGL(kA, dim3(320), dim3(256), 0, stream, hstates, pos, vel, bpos, Ws, bs,
                     Wv, bv, Wm1, bm1, Wm2, Wp, ws);
  hipLaunchKernelGGL(kC, dim3(NSC * 32), dim3(256), 0, stream, ws, bm2);
  hipLaunchKernelGGL(kD, dim3(NTOT / 16), dim3(256), 0, stream, ws, bp, out);
}